// Round 11
// baseline (314.876 us; speedup 1.0000x reference)
//
#include <hip/hip_runtime.h>
#include <hip/hip_bf16.h>
#include <stdint.h>

#define NIN    100000
#define NOUT   200000
#define KOFF   27
#define C      64
#define NPAIR  (KOFF * NIN)            // 2,700,000
#define EPS    1e-5f
#define NBUK   ((NOUT + 255) / 256)    // 782 buckets of 256 output rows
#define IPB    4096                    // items per bin_sort block
#define RPB    128                     // rows per gather sub-block
#define SIT    3072                    // sorted-item capacity per sub-block

typedef __attribute__((ext_vector_type(8))) short bf16x8;
typedef __attribute__((ext_vector_type(4))) float f32x4;

// ---------------- fp32 -> bf16 conversion (8 elems / thread) ---------------
__global__ __launch_bounds__(256)
void cvt_bf16_kernel(const float* __restrict__ src, ushort* __restrict__ dst, int n8)
{
    int t = blockIdx.x * 256 + threadIdx.x;
    if (t >= n8) return;
    const float4* s4 = reinterpret_cast<const float4*>(src) + (size_t)t * 2;
    float4 a = s4[0], b = s4[1];
    float v[8] = {a.x, a.y, a.z, a.w, b.x, b.y, b.z, b.w};
    union { ushort u[8]; uint4 q; } pk;
    #pragma unroll
    for (int j = 0; j < 8; ++j) {
        __hip_bfloat16 h = __float2bfloat16(v[j]);
        pk.u[j] = *reinterpret_cast<ushort*>(&h);
    }
    reinterpret_cast<uint4*>(dst)[t] = pk.q;
}

// ---------------- Phase A: MFMA GEMM  P_chunk[lk] = feats @ W[k0+lk] -------
// Wave = 16-row M-tile x 64 channels for one offset. Operand-swapped MFMA:
// lane l, reg r holds out[row = lane&15][chan = nt*16 + (lane>>4)*4 + r].
__global__ __launch_bounds__(256)
void gemm_mfma_kernel(const ushort* __restrict__ featsb,   // [NIN][C] bf16
                      const ushort* __restrict__ weightb,  // [KOFF][C][C] bf16
                      ushort* __restrict__ P,              // [kcnt][NIN][C] bf16
                      int k0)
{
    const int lk   = blockIdx.y;
    const int k    = k0 + lk;
    const int lane = threadIdx.x & 63;
    const int wave = threadIdx.x >> 6;
    const int m16  = lane & 15;
    const int q    = lane >> 4;        // 0..3

    const ushort* wb = weightb + (size_t)k * C * C;
    bf16x8 xf[4][2];
    #pragma unroll
    for (int nt = 0; nt < 4; ++nt)
        #pragma unroll
        for (int kc = 0; kc < 2; ++kc)
            #pragma unroll
            for (int j = 0; j < 8; ++j)
                xf[nt][kc][j] = (short)wb[(size_t)(kc * 32 + 8 * q + j) * C + nt * 16 + m16];

    ushort* Pk = P + (size_t)lk * NIN * C;
    const int tiles = NIN / 16;        // 6250 exactly

    for (int tile = blockIdx.x * 4 + wave; tile < tiles; tile += gridDim.x * 4) {
        const int mbase = tile * 16;
        const ushort* fr = featsb + (size_t)(mbase + m16) * C;
        bf16x8 y0 = *reinterpret_cast<const bf16x8*>(fr + 8 * q);
        bf16x8 y1 = *reinterpret_cast<const bf16x8*>(fr + 32 + 8 * q);

        f32x4 acc0 = {0,0,0,0}, acc1 = {0,0,0,0}, acc2 = {0,0,0,0}, acc3 = {0,0,0,0};
        acc0 = __builtin_amdgcn_mfma_f32_16x16x32_bf16(xf[0][0], y0, acc0, 0, 0, 0);
        acc1 = __builtin_amdgcn_mfma_f32_16x16x32_bf16(xf[1][0], y0, acc1, 0, 0, 0);
        acc2 = __builtin_amdgcn_mfma_f32_16x16x32_bf16(xf[2][0], y0, acc2, 0, 0, 0);
        acc3 = __builtin_amdgcn_mfma_f32_16x16x32_bf16(xf[3][0], y0, acc3, 0, 0, 0);
        acc0 = __builtin_amdgcn_mfma_f32_16x16x32_bf16(xf[0][1], y1, acc0, 0, 0, 0);
        acc1 = __builtin_amdgcn_mfma_f32_16x16x32_bf16(xf[1][1], y1, acc1, 0, 0, 0);
        acc2 = __builtin_amdgcn_mfma_f32_16x16x32_bf16(xf[2][1], y1, acc2, 0, 0, 0);
        acc3 = __builtin_amdgcn_mfma_f32_16x16x32_bf16(xf[3][1], y1, acc3, 0, 0, 0);

        ushort* prow = Pk + (size_t)(mbase + m16) * C;
        f32x4 accs[4] = {acc0, acc1, acc2, acc3};
        #pragma unroll
        for (int nt = 0; nt < 4; ++nt) {
            union { ushort u[4]; uint2 v; } pk;
            #pragma unroll
            for (int r = 0; r < 4; ++r) {
                __hip_bfloat16 h = __float2bfloat16(accs[nt][r]);
                pk.u[r] = *reinterpret_cast<ushort*>(&h);
            }
            *reinterpret_cast<uint2*>(prow + nt * 16 + q * 4) = pk.v;
        }
    }
}

// ---------------- Phase B: block-local bucket sort (streaming writes) ------
// Each block owns items [t0, t0+IPB) of its group, counting-sorts them by
// bucket (out row >> 8) in LDS, streams the sorted block to its PRIVATE
// region binned[(g*NBF+blk)*IPB ..], and writes its bucket-offset table
// boffs[(g*NBF+blk)][0..NBUK] (ushort). No global cursors, no scatter, no
// overflow possible.
// Payload: bits[0,17)=ii  bits[17,21)=lk (group-local k)  bits[21,29)=oi&255.
__global__ __launch_bounds__(256)
void bin_sort_kernel(const int* __restrict__ in_idx, const int* __restrict__ out_idx,
                     uint32_t* __restrict__ binned, ushort* __restrict__ boffs,
                     int kpg, int nbf)
{
    __shared__ uint32_t staged[IPB];
    __shared__ int hist[NBUK];
    __shared__ int base[NBUK + 1];
    __shared__ int cur[NBUK];
    __shared__ int s[256];

    const int g    = blockIdx.y;
    const int blk  = blockIdx.x;
    const int t    = threadIdx.x;
    const int kbeg = g * kpg;
    const int t0   = kbeg * NIN + blk * IPB;
    int tend = (g + 1) * kpg * NIN;
    if (tend > NPAIR) tend = NPAIR;
    int n = tend - t0;
    if (n < 0) n = 0;
    if (n > IPB) n = IPB;

    for (int i = t; i < NBUK; i += 256) hist[i] = 0;
    __syncthreads();

    // pass 1: histogram by bucket
    for (int i = t; i < n; i += 256)
        atomicAdd(&hist[out_idx[t0 + i] >> 8], 1);
    __syncthreads();

    // in-block exclusive scan over NBUK buckets (per-thread chunk of 4)
    {
        int local[4];
        int sum = 0;
        #pragma unroll
        for (int j = 0; j < 4; ++j) {
            int idx = t * 4 + j;
            int v = (idx < NBUK) ? hist[idx] : 0;
            local[j] = sum;
            sum += v;
        }
        s[t] = sum;
        __syncthreads();
        for (int off = 1; off < 256; off <<= 1) {
            int x = (t >= off) ? s[t - off] : 0;
            __syncthreads();
            s[t] += x;
            __syncthreads();
        }
        int tbase = (t > 0) ? s[t - 1] : 0;
        #pragma unroll
        for (int j = 0; j < 4; ++j) {
            int idx = t * 4 + j;
            if (idx < NBUK) {
                int o = tbase + local[j];
                base[idx] = o;
                cur[idx]  = o;
            }
        }
        if (t == 255) base[NBUK] = s[255];
    }
    __syncthreads();

    // pass 2: place payloads into staged[] in bucket order
    for (int i = t; i < n; i += 256) {
        int tt  = t0 + i;
        int oi  = out_idx[tt];
        int k   = tt / NIN;
        int pos = atomicAdd(&cur[oi >> 8], 1);
        staged[pos] = ((uint32_t)(oi & 255) << 21)
                    | ((uint32_t)(k - kbeg) << 17)
                    | (uint32_t)in_idx[tt];
    }
    __syncthreads();

    // stream out: sorted payloads (full-line writes) + offset table
    uint32_t* dst = binned + (size_t)(g * nbf + blk) * IPB;
    for (int i = t; i < n; i += 256) dst[i] = staged[i];
    ushort* bo = boffs + (size_t)(g * nbf + blk) * (NBUK + 1);
    for (int i = t; i <= NBUK; i += 256) bo[i] = (ushort)base[i];
}

// ---------------- Phase C: per-half-bucket LDS sort + gather + BN/ReLU -----
// Block = (bucket b, half sub): 128 output rows. Walk this bucket's runs in
// all nbf source-block regions (thread r owns run r), counting-sort by row,
// then 16 threads/row reduce P rows with 4-deep load ILP.
__global__ __launch_bounds__(256)
void gather_bucket_kernel(const uint2* __restrict__ P2,
                          const uint32_t* __restrict__ binned,
                          const ushort* __restrict__ boffs,
                          int nbf, int gblk0,
                          const float* __restrict__ gamma,
                          const float* __restrict__ beta,
                          const float* __restrict__ mean,
                          const float* __restrict__ var,
                          float* __restrict__ out,
                          int accumulate, int finalize)
{
    __shared__ uint32_t sIt[SIT];
    __shared__ int sCnt[RPB];
    __shared__ int sOff[RPB + 1];
    __shared__ int sCur[RPB];

    const int b   = blockIdx.x;
    const int sub = blockIdx.y;                  // 0/1 -> rows [sub*128, +128)
    const int t   = threadIdx.x;
    const int rlo = sub * RPB;

    if (t < RPB) sCnt[t] = 0;
    __syncthreads();

    // pass 1: count rows in this half across all runs of bucket b
    for (int r = t; r < nbf; r += 256) {
        const ushort* bo = boffs + (size_t)(gblk0 + r) * (NBUK + 1) + b;
        const int o0 = bo[0], o1 = bo[1];
        const uint32_t* src = binned + (size_t)(gblk0 + r) * IPB;
        for (int i = o0; i < o1; ++i) {
            int rl = (int)(src[i] >> 21) - rlo;
            if ((unsigned)rl < (unsigned)RPB) atomicAdd(&sCnt[rl], 1);
        }
    }
    __syncthreads();
    // inclusive scan over RPB entries (first 128 threads)
    if (t < RPB) sOff[t + 1] = sCnt[t];
    __syncthreads();
    for (int off = 1; off < RPB; off <<= 1) {
        int x = 0;
        if (t < RPB && t >= off) x = sOff[t + 1 - off];
        __syncthreads();
        if (t < RPB) sOff[t + 1] += x;
        __syncthreads();
    }
    if (t == 0) sOff[0] = 0;
    __syncthreads();
    if (t < RPB) sCur[t] = sOff[t + 1] - sCnt[t];
    __syncthreads();
    // pass 2: place into sIt sorted by row
    for (int r = t; r < nbf; r += 256) {
        const ushort* bo = boffs + (size_t)(gblk0 + r) * (NBUK + 1) + b;
        const int o0 = bo[0], o1 = bo[1];
        const uint32_t* src = binned + (size_t)(gblk0 + r) * IPB;
        for (int i = o0; i < o1; ++i) {
            uint32_t pl = src[i];
            int rl = (int)(pl >> 21) - rlo;
            if ((unsigned)rl < (unsigned)RPB) {
                int slot = atomicAdd(&sCur[rl], 1);
                if (slot < SIT) sIt[slot] = pl;
            }
        }
    }
    __syncthreads();

    const int cp = t & 15;
    const int c0 = cp * 4;
    float sc[4], sh[4];
    if (finalize) {
        #pragma unroll
        for (int r = 0; r < 4; ++r) {
            const int c = c0 + r;
            float s = gamma[c] * rsqrtf(var[c] + EPS);
            sc[r] = s;
            sh[r] = beta[c] - mean[c] * s;
        }
    }

    float4* out4 = reinterpret_cast<float4*>(out);
    #pragma unroll 1
    for (int it = 0; it < RPB / 16; ++it) {
        const int rl  = (t >> 4) + it * 16;
        const int row = b * 256 + rlo + rl;
        if (row >= NOUT) continue;
        int j  = sOff[rl];
        const int je = sOff[rl + 1];

        float a0 = 0.f, a1 = 0.f, a2 = 0.f, a3 = 0.f;
        for (; j + 3 < je; j += 4) {              // 4 loads in flight
            uint32_t p0 = sIt[j],     p1 = sIt[j + 1];
            uint32_t p2 = sIt[j + 2], p3 = sIt[j + 3];
            uint2 u0 = P2[((size_t)((p0 >> 17) & 15) * NIN + (p0 & 0x1FFFF)) * 16 + cp];
            uint2 u1 = P2[((size_t)((p1 >> 17) & 15) * NIN + (p1 & 0x1FFFF)) * 16 + cp];
            uint2 u2 = P2[((size_t)((p2 >> 17) & 15) * NIN + (p2 & 0x1FFFF)) * 16 + cp];
            uint2 u3 = P2[((size_t)((p3 >> 17) & 15) * NIN + (p3 & 0x1FFFF)) * 16 + cp];
            a0 += __uint_as_float(u0.x << 16);
            a1 += __uint_as_float(u0.x & 0xffff0000u);
            a2 += __uint_as_float(u0.y << 16);
            a3 += __uint_as_float(u0.y & 0xffff0000u);
            a0 += __uint_as_float(u1.x << 16);
            a1 += __uint_as_float(u1.x & 0xffff0000u);
            a2 += __uint_as_float(u1.y << 16);
            a3 += __uint_as_float(u1.y & 0xffff0000u);
            a0 += __uint_as_float(u2.x << 16);
            a1 += __uint_as_float(u2.x & 0xffff0000u);
            a2 += __uint_as_float(u2.y << 16);
            a3 += __uint_as_float(u2.y & 0xffff0000u);
            a0 += __uint_as_float(u3.x << 16);
            a1 += __uint_as_float(u3.x & 0xffff0000u);
            a2 += __uint_as_float(u3.y << 16);
            a3 += __uint_as_float(u3.y & 0xffff0000u);
        }
        for (; j < je; ++j) {
            uint32_t p0 = sIt[j];
            uint2 u0 = P2[((size_t)((p0 >> 17) & 15) * NIN + (p0 & 0x1FFFF)) * 16 + cp];
            a0 += __uint_as_float(u0.x << 16);
            a1 += __uint_as_float(u0.x & 0xffff0000u);
            a2 += __uint_as_float(u0.y << 16);
            a3 += __uint_as_float(u0.y & 0xffff0000u);
        }

        const size_t oidx = (size_t)row * 16 + cp;
        if (accumulate) {
            float4 pv = out4[oidx];
            a0 += pv.x; a1 += pv.y; a2 += pv.z; a3 += pv.w;
        }
        if (finalize) {
            a0 = fmaf(a0, sc[0], sh[0]); a0 = a0 > 0.f ? a0 : 0.f;
            a1 = fmaf(a1, sc[1], sh[1]); a1 = a1 > 0.f ? a1 : 0.f;
            a2 = fmaf(a2, sc[2], sh[2]); a2 = a2 > 0.f ? a2 : 0.f;
            a3 = fmaf(a3, sc[3], sh[3]); a3 = a3 > 0.f ? a3 : 0.f;
        }
        out4[oidx] = make_float4(a0, a1, a2, a3);
    }
}

// ---------------- Fallback (atomic path, tiny ws) --------------------------
__global__ __launch_bounds__(256)
void conv_scatter_kernel(const float* __restrict__ feats,
                         const float* __restrict__ weight,
                         const int*   __restrict__ in_idx,
                         const int*   __restrict__ out_idx,
                         float*       __restrict__ out)
{
    const int k    = blockIdx.y;
    const int lane = threadIdx.x & 63;
    const int wave = threadIdx.x >> 6;
    const int wavesInGrid = gridDim.x * 4;
    const int waveId      = blockIdx.x * 4 + wave;

    const float* wk = weight + (size_t)k * C * C + lane;
    float w[C];
    #pragma unroll
    for (int ci = 0; ci < C; ++ci) w[ci] = wk[(size_t)ci * C];

    const int* ii_k = in_idx  + (size_t)k * NIN;
    const int* oi_k = out_idx + (size_t)k * NIN;

    for (int r = waveId; r < NIN; r += wavesInGrid) {
        const int ii = ii_k[r];
        const int oi = oi_k[r];
        const float4* frow = reinterpret_cast<const float4*>(feats + (size_t)ii * C);
        float acc = 0.0f;
        #pragma unroll
        for (int j = 0; j < C / 4; ++j) {
            float4 f = frow[j];
            acc = fmaf(f.x, w[4 * j + 0], acc);
            acc = fmaf(f.y, w[4 * j + 1], acc);
            acc = fmaf(f.z, w[4 * j + 2], acc);
            acc = fmaf(f.w, w[4 * j + 3], acc);
        }
        atomicAdd(out + (size_t)oi * C + lane, acc);
    }
}

__global__ __launch_bounds__(256)
void bn_relu_kernel(float* __restrict__ out,
                    const float* __restrict__ gamma,
                    const float* __restrict__ beta,
                    const float* __restrict__ mean,
                    const float* __restrict__ var)
{
    const int total4 = NOUT * C / 4;
    int idx = blockIdx.x * blockDim.x + threadIdx.x;
    if (idx >= total4) return;
    const int c0 = (idx * 4) & (C - 1);
    float sc[4], sh[4];
    #pragma unroll
    for (int j = 0; j < 4; ++j) {
        const int c  = c0 + j;
        const float s = gamma[c] * rsqrtf(var[c] + EPS);
        sc[j] = s;
        sh[j] = beta[c] - mean[c] * s;
    }
    float4* p = reinterpret_cast<float4*>(out) + idx;
    float4 v = *p;
    v.x = fmaf(v.x, sc[0], sh[0]); v.x = v.x > 0.f ? v.x : 0.f;
    v.y = fmaf(v.y, sc[1], sh[1]); v.y = v.y > 0.f ? v.y : 0.f;
    v.z = fmaf(v.z, sc[2], sh[2]); v.z = v.z > 0.f ? v.z : 0.f;
    v.w = fmaf(v.w, sc[3], sh[3]); v.w = v.w > 0.f ? v.w : 0.f;
    *p = v;
}

// ---------------------------------------------------------------------------
extern "C" void kernel_launch(void* const* d_in, const int* in_sizes, int n_in,
                              void* d_out, int out_size, void* d_ws, size_t ws_size,
                              hipStream_t stream) {
    const float* feats   = (const float*)d_in[0];
    const float* weight  = (const float*)d_in[1];
    const int*   in_idx  = (const int*)  d_in[2];
    const int*   out_idx = (const int*)  d_in[3];
    const float* gamma   = (const float*)d_in[4];
    const float* beta    = (const float*)d_in[5];
    const float* rmean   = (const float*)d_in[6];
    const float* rvar    = (const float*)d_in[7];
    float* out = (float*)d_out;

    auto align = [](size_t x) { return (x + 255) & ~(size_t)255; };

    // kpg=9 (G=3): P chunk 115 MB stays L3-resident for the gemm write /
    // gather read; one fewer out-RMW pass than G=4 (round-8/9 comparison).
    int kpg = 0, G = 0, NBF = 0;
    size_t oBin = 0, oBo = 0, oFb = 0, oWb = 0, oP = 0;
    for (int t = 9; t >= 1; --t) {
        int g   = (KOFF + t - 1) / t;
        int nbf = (t * NIN + IPB - 1) / IPB;
        size_t a = 0;
        size_t bi = a; a += align((size_t)g * nbf * IPB * 4);         // binned regions
        size_t bo = a; a += align((size_t)g * nbf * (NBUK + 1) * 2);  // boffs ushort
        size_t fb = a; a += align((size_t)NIN * C * 2);               // feats bf16
        size_t wb = a; a += align((size_t)KOFF * C * C * 2);          // weight bf16
        size_t q_ = a; a += align((size_t)t * NIN * C * 2);           // P_chunk bf16
        if (a <= ws_size) {
            kpg = t; G = g; NBF = nbf;
            oBin = bi; oBo = bo; oFb = fb; oWb = wb; oP = q_;
            break;
        }
    }

    if (kpg == 0) {
        hipMemsetAsync(out, 0, (size_t)out_size * sizeof(float), stream);
        dim3 grid(512, KOFF);
        conv_scatter_kernel<<<grid, 256, 0, stream>>>(feats, weight, in_idx, out_idx, out);
        const int total4 = NOUT * C / 4;
        bn_relu_kernel<<<(total4 + 255) / 256, 256, 0, stream>>>(out, gamma, beta, rmean, rvar);
        return;
    }

    char* ws = (char*)d_ws;
    uint32_t* binned = (uint32_t*)(ws + oBin);
    ushort* boffs    = (ushort*)(ws + oBo);
    ushort* featsb   = (ushort*)(ws + oFb);
    ushort* weightb  = (ushort*)(ws + oWb);
    ushort* P        = (ushort*)(ws + oP);

    // --- bf16 conversions ---
    {
        int n8f = NIN * C / 8;
        cvt_bf16_kernel<<<(n8f + 255) / 256, 256, 0, stream>>>(feats, featsb, n8f);
        int n8w = KOFF * C * C / 8;
        cvt_bf16_kernel<<<(n8w + 255) / 256, 256, 0, stream>>>(weight, weightb, n8w);
    }

    // --- Block-local bucket sort (streaming writes, no global cursors) ---
    {
        dim3 gS(NBF, G);
        bin_sort_kernel<<<gS, 256, 0, stream>>>(in_idx, out_idx, binned, boffs,
                                                kpg, NBF);
    }

    // --- Per-group: MFMA GEMM chunk, then half-bucket gather into out ---
    for (int g = 0; g < G; ++g) {
        const int k0   = g * kpg;
        const int kcnt = (k0 + kpg <= KOFF) ? kpg : (KOFF - k0);

        dim3 grid(128, kcnt);
        gemm_mfma_kernel<<<grid, 256, 0, stream>>>(featsb, weightb, P, k0);

        dim3 ggrid(NBUK, 2);
        gather_bucket_kernel<<<ggrid, 256, 0, stream>>>(
            (const uint2*)P, binned, boffs, NBF, g * NBF,
            gamma, beta, rmean, rvar, out,
            /*accumulate=*/(g > 0), /*finalize=*/(g == G - 1));
    }
}

// Round 12
// 283.129 us; speedup vs baseline: 1.1121x; 1.1121x over previous
//
#include <hip/hip_runtime.h>
#include <hip/hip_bf16.h>
#include <stdint.h>

#define NIN    100000
#define NOUT   200000
#define KOFF   27
#define C      64
#define NPAIR  (KOFF * NIN)            // 2,700,000
#define EPS    1e-5f
#define NCRS   196                     // coarse buckets of 1024 output rows
#define CAPC   5760                    // per-(group,coarse) capacity (mean 4592 @kpg=9, +17 sigma)
#define IPB_F  4096                    // items per bin_coarse block
#define RPF    128                     // rows per fine bucket
#define SIT    1024                    // sorted-item capacity per fine bucket (mean 574)

typedef __attribute__((ext_vector_type(8))) short bf16x8;
typedef __attribute__((ext_vector_type(4))) float f32x4;

// ---------------- fp32 -> bf16 conversion (8 elems / thread) ---------------
__global__ __launch_bounds__(256)
void cvt_bf16_kernel(const float* __restrict__ src, ushort* __restrict__ dst, int n8)
{
    int t = blockIdx.x * 256 + threadIdx.x;
    if (t >= n8) return;
    const float4* s4 = reinterpret_cast<const float4*>(src) + (size_t)t * 2;
    float4 a = s4[0], b = s4[1];
    float v[8] = {a.x, a.y, a.z, a.w, b.x, b.y, b.z, b.w};
    union { ushort u[8]; uint4 q; } pk;
    #pragma unroll
    for (int j = 0; j < 8; ++j) {
        __hip_bfloat16 h = __float2bfloat16(v[j]);
        pk.u[j] = *reinterpret_cast<ushort*>(&h);
    }
    reinterpret_cast<uint4*>(dst)[t] = pk.q;
}

// ---------------- Phase A: MFMA GEMM  P_chunk[lk] = feats @ W[k0+lk] -------
__global__ __launch_bounds__(256)
void gemm_mfma_kernel(const ushort* __restrict__ featsb,   // [NIN][C] bf16
                      const ushort* __restrict__ weightb,  // [KOFF][C][C] bf16
                      ushort* __restrict__ P,              // [kcnt][NIN][C] bf16
                      int k0)
{
    const int lk   = blockIdx.y;
    const int k    = k0 + lk;
    const int lane = threadIdx.x & 63;
    const int wave = threadIdx.x >> 6;
    const int m16  = lane & 15;
    const int q    = lane >> 4;        // 0..3

    const ushort* wb = weightb + (size_t)k * C * C;
    bf16x8 xf[4][2];
    #pragma unroll
    for (int nt = 0; nt < 4; ++nt)
        #pragma unroll
        for (int kc = 0; kc < 2; ++kc)
            #pragma unroll
            for (int j = 0; j < 8; ++j)
                xf[nt][kc][j] = (short)wb[(size_t)(kc * 32 + 8 * q + j) * C + nt * 16 + m16];

    ushort* Pk = P + (size_t)lk * NIN * C;
    const int tiles = NIN / 16;        // 6250 exactly

    for (int tile = blockIdx.x * 4 + wave; tile < tiles; tile += gridDim.x * 4) {
        const int mbase = tile * 16;
        const ushort* fr = featsb + (size_t)(mbase + m16) * C;
        bf16x8 y0 = *reinterpret_cast<const bf16x8*>(fr + 8 * q);
        bf16x8 y1 = *reinterpret_cast<const bf16x8*>(fr + 32 + 8 * q);

        f32x4 acc0 = {0,0,0,0}, acc1 = {0,0,0,0}, acc2 = {0,0,0,0}, acc3 = {0,0,0,0};
        acc0 = __builtin_amdgcn_mfma_f32_16x16x32_bf16(xf[0][0], y0, acc0, 0, 0, 0);
        acc1 = __builtin_amdgcn_mfma_f32_16x16x32_bf16(xf[1][0], y0, acc1, 0, 0, 0);
        acc2 = __builtin_amdgcn_mfma_f32_16x16x32_bf16(xf[2][0], y0, acc2, 0, 0, 0);
        acc3 = __builtin_amdgcn_mfma_f32_16x16x32_bf16(xf[3][0], y0, acc3, 0, 0, 0);
        acc0 = __builtin_amdgcn_mfma_f32_16x16x32_bf16(xf[0][1], y1, acc0, 0, 0, 0);
        acc1 = __builtin_amdgcn_mfma_f32_16x16x32_bf16(xf[1][1], y1, acc1, 0, 0, 0);
        acc2 = __builtin_amdgcn_mfma_f32_16x16x32_bf16(xf[2][1], y1, acc2, 0, 0, 0);
        acc3 = __builtin_amdgcn_mfma_f32_16x16x32_bf16(xf[3][1], y1, acc3, 0, 0, 0);

        ushort* prow = Pk + (size_t)(mbase + m16) * C;
        f32x4 accs[4] = {acc0, acc1, acc2, acc3};
        #pragma unroll
        for (int nt = 0; nt < 4; ++nt) {
            union { ushort u[4]; uint2 v; } pk;
            #pragma unroll
            for (int r = 0; r < 4; ++r) {
                __hip_bfloat16 h = __float2bfloat16(accs[nt][r]);
                pk.u[r] = *reinterpret_cast<ushort*>(&h);
            }
            *reinterpret_cast<uint2*>(prow + nt * 16 + q * 4) = pk.v;
        }
    }
}

// ---------------- Phase B1: coarse binning (1024-row buckets) --------------
// Segment (g,cb) at binned[(g*NCRS+cb)*CAPC ..). Runs of ~21 items per block
// per bucket -> write amp ~1.3x. gcur is reservation cursor AND final count.
// Payload: bits[0,17)=ii  bits[17,21)=lk  bits[21,31)=oi&1023 (row in coarse).
__global__ __launch_bounds__(256)
void bin_coarse_kernel(const int* __restrict__ in_idx, const int* __restrict__ out_idx,
                       int* __restrict__ gcur, uint32_t* __restrict__ binned,
                       int kpg)
{
    __shared__ int hist[NCRS];
    __shared__ int base[NCRS];
    const int g    = blockIdx.y;
    const int kbeg = g * kpg;
    const int tbeg = kbeg * NIN;
    int tend = (g + 1) * kpg * NIN;
    if (tend > NPAIR) tend = NPAIR;

    for (int i = threadIdx.x; i < NCRS; i += 256) hist[i] = 0;
    __syncthreads();
    const int t0 = tbeg + blockIdx.x * IPB_F;
    #pragma unroll 4
    for (int j = 0; j < IPB_F / 256; ++j) {
        int t = t0 + j * 256 + threadIdx.x;
        if (t < tend) atomicAdd(&hist[out_idx[t] >> 10], 1);
    }
    __syncthreads();
    int* gc = gcur + (size_t)g * NCRS;
    for (int i = threadIdx.x; i < NCRS; i += 256) {
        int c = hist[i];
        base[i] = c ? atomicAdd(&gc[i], c) : 0;
    }
    __syncthreads();
    #pragma unroll 4
    for (int j = 0; j < IPB_F / 256; ++j) {
        int t = t0 + j * 256 + threadIdx.x;
        if (t < tend) {
            int k   = t / NIN;
            int oi  = out_idx[t];
            int ii  = in_idx[t];
            int cb  = oi >> 10;
            int p   = atomicSub(&hist[cb], 1) - 1;
            int pos = base[cb] + p;
            if (pos < CAPC) {
                uint32_t payload = ((uint32_t)(oi & 1023) << 21)
                                 | ((uint32_t)(k - kbeg) << 17)
                                 | (uint32_t)ii;
                binned[((size_t)g * NCRS + cb) * CAPC + pos] = payload;
            }
        }
    }
}

// ---------------- Phase B2: fine sort within coarse segment (in place) -----
// One block per (g, cb): counting-sort ~4.6K items by fine bucket
// ((row10>>7)&7, 128 rows each) in LDS, stream back to the SAME segment
// (reads complete before writes within the block), emit 9-entry offset table.
__global__ __launch_bounds__(256)
void bin_fine_kernel(const int* __restrict__ gcur, uint32_t* __restrict__ binned,
                     int* __restrict__ foff)
{
    __shared__ uint32_t staged[CAPC];
    __shared__ int hist8[8], base8[9], cur8[8];

    const int g  = blockIdx.y;
    const int cb = blockIdx.x;
    const int t  = threadIdx.x;
    const size_t segoff = ((size_t)g * NCRS + cb) * CAPC;
    uint32_t* seg = binned + segoff;
    int n = gcur[g * NCRS + cb];
    if (n > CAPC) n = CAPC;

    if (t < 8) hist8[t] = 0;
    __syncthreads();
    for (int i = t; i < n; i += 256)
        atomicAdd(&hist8[(seg[i] >> 28) & 7], 1);
    __syncthreads();
    if (t == 0) {
        int s = 0;
        #pragma unroll
        for (int b = 0; b < 8; ++b) { base8[b] = s; s += hist8[b]; }
        base8[8] = s;
    }
    __syncthreads();
    if (t < 8) cur8[t] = base8[t];
    __syncthreads();
    for (int i = t; i < n; i += 256) {
        uint32_t pl = seg[i];
        int pos = atomicAdd(&cur8[(pl >> 28) & 7], 1);
        staged[pos] = pl;
    }
    __syncthreads();
    for (int i = t; i < n; i += 256) seg[i] = staged[i];
    if (t <= 8) foff[((size_t)g * NCRS + cb) * 9 + t] = base8[t];
}

// ---------------- Phase C: per-fine-bucket gather + BN/ReLU ----------------
// Block = (cb, fb): 128 output rows, reads ONLY its contiguous fine run.
// Counting-sort by row, then 16 threads/row reduce P rows with 4-deep ILP.
__global__ __launch_bounds__(256)
void gather_bucket_kernel(const uint2* __restrict__ P2,
                          const uint32_t* __restrict__ binned,
                          const int* __restrict__ foff, int gbase,
                          const float* __restrict__ gamma,
                          const float* __restrict__ beta,
                          const float* __restrict__ mean,
                          const float* __restrict__ var,
                          float* __restrict__ out,
                          int accumulate, int finalize)
{
    __shared__ uint32_t sIt[SIT];
    __shared__ int sCnt[RPF];
    __shared__ int sOff[RPF + 1];
    __shared__ int sCur[RPF];

    const int cb = blockIdx.x;
    const int fb = blockIdx.y;                   // 0..7
    const int t  = threadIdx.x;
    const int* fo = foff + ((size_t)(gbase + cb)) * 9;
    const int js = fo[fb], je = fo[fb + 1];
    const uint32_t* seg = binned + ((size_t)(gbase + cb)) * CAPC;

    if (t < RPF) sCnt[t] = 0;
    __syncthreads();
    for (int i = js + t; i < je; i += 256)
        atomicAdd(&sCnt[(seg[i] >> 21) & 127], 1);
    __syncthreads();
    if (t < RPF) sOff[t + 1] = sCnt[t];
    __syncthreads();
    for (int off = 1; off < RPF; off <<= 1) {
        int x = 0;
        if (t < RPF && t >= off) x = sOff[t + 1 - off];
        __syncthreads();
        if (t < RPF) sOff[t + 1] += x;
        __syncthreads();
    }
    if (t == 0) sOff[0] = 0;
    __syncthreads();
    if (t < RPF) sCur[t] = sOff[t + 1] - sCnt[t];
    __syncthreads();
    for (int i = js + t; i < je; i += 256) {
        uint32_t pl = seg[i];
        int slot = atomicAdd(&sCur[(pl >> 21) & 127], 1);
        if (slot < SIT) sIt[slot] = pl;
    }
    __syncthreads();

    const int cp = t & 15;
    const int c0 = cp * 4;
    float sc[4], sh[4];
    if (finalize) {
        #pragma unroll
        for (int r = 0; r < 4; ++r) {
            const int c = c0 + r;
            float s = gamma[c] * rsqrtf(var[c] + EPS);
            sc[r] = s;
            sh[r] = beta[c] - mean[c] * s;
        }
    }

    float4* out4 = reinterpret_cast<float4*>(out);
    #pragma unroll 1
    for (int it = 0; it < RPF / 16; ++it) {
        const int rl  = (t >> 4) + it * 16;
        const int row = cb * 1024 + fb * 128 + rl;
        if (row >= NOUT) continue;
        int j  = sOff[rl];
        const int jend = sOff[rl + 1];

        float a0 = 0.f, a1 = 0.f, a2 = 0.f, a3 = 0.f;
        for (; j + 3 < jend; j += 4) {            // 4 loads in flight
            uint32_t p0 = sIt[j],     p1 = sIt[j + 1];
            uint32_t p2 = sIt[j + 2], p3 = sIt[j + 3];
            uint2 u0 = P2[((size_t)((p0 >> 17) & 15) * NIN + (p0 & 0x1FFFF)) * 16 + cp];
            uint2 u1 = P2[((size_t)((p1 >> 17) & 15) * NIN + (p1 & 0x1FFFF)) * 16 + cp];
            uint2 u2 = P2[((size_t)((p2 >> 17) & 15) * NIN + (p2 & 0x1FFFF)) * 16 + cp];
            uint2 u3 = P2[((size_t)((p3 >> 17) & 15) * NIN + (p3 & 0x1FFFF)) * 16 + cp];
            a0 += __uint_as_float(u0.x << 16);
            a1 += __uint_as_float(u0.x & 0xffff0000u);
            a2 += __uint_as_float(u0.y << 16);
            a3 += __uint_as_float(u0.y & 0xffff0000u);
            a0 += __uint_as_float(u1.x << 16);
            a1 += __uint_as_float(u1.x & 0xffff0000u);
            a2 += __uint_as_float(u1.y << 16);
            a3 += __uint_as_float(u1.y & 0xffff0000u);
            a0 += __uint_as_float(u2.x << 16);
            a1 += __uint_as_float(u2.x & 0xffff0000u);
            a2 += __uint_as_float(u2.y << 16);
            a3 += __uint_as_float(u2.y & 0xffff0000u);
            a0 += __uint_as_float(u3.x << 16);
            a1 += __uint_as_float(u3.x & 0xffff0000u);
            a2 += __uint_as_float(u3.y << 16);
            a3 += __uint_as_float(u3.y & 0xffff0000u);
        }
        for (; j < jend; ++j) {
            uint32_t p0 = sIt[j];
            uint2 u0 = P2[((size_t)((p0 >> 17) & 15) * NIN + (p0 & 0x1FFFF)) * 16 + cp];
            a0 += __uint_as_float(u0.x << 16);
            a1 += __uint_as_float(u0.x & 0xffff0000u);
            a2 += __uint_as_float(u0.y << 16);
            a3 += __uint_as_float(u0.y & 0xffff0000u);
        }

        const size_t oidx = (size_t)row * 16 + cp;
        if (accumulate) {
            float4 pv = out4[oidx];
            a0 += pv.x; a1 += pv.y; a2 += pv.z; a3 += pv.w;
        }
        if (finalize) {
            a0 = fmaf(a0, sc[0], sh[0]); a0 = a0 > 0.f ? a0 : 0.f;
            a1 = fmaf(a1, sc[1], sh[1]); a1 = a1 > 0.f ? a1 : 0.f;
            a2 = fmaf(a2, sc[2], sh[2]); a2 = a2 > 0.f ? a2 : 0.f;
            a3 = fmaf(a3, sc[3], sh[3]); a3 = a3 > 0.f ? a3 : 0.f;
        }
        out4[oidx] = make_float4(a0, a1, a2, a3);
    }
}

// ---------------- Fallback (atomic path, tiny ws) --------------------------
__global__ __launch_bounds__(256)
void conv_scatter_kernel(const float* __restrict__ feats,
                         const float* __restrict__ weight,
                         const int*   __restrict__ in_idx,
                         const int*   __restrict__ out_idx,
                         float*       __restrict__ out)
{
    const int k    = blockIdx.y;
    const int lane = threadIdx.x & 63;
    const int wave = threadIdx.x >> 6;
    const int wavesInGrid = gridDim.x * 4;
    const int waveId      = blockIdx.x * 4 + wave;

    const float* wk = weight + (size_t)k * C * C + lane;
    float w[C];
    #pragma unroll
    for (int ci = 0; ci < C; ++ci) w[ci] = wk[(size_t)ci * C];

    const int* ii_k = in_idx  + (size_t)k * NIN;
    const int* oi_k = out_idx + (size_t)k * NIN;

    for (int r = waveId; r < NIN; r += wavesInGrid) {
        const int ii = ii_k[r];
        const int oi = oi_k[r];
        const float4* frow = reinterpret_cast<const float4*>(feats + (size_t)ii * C);
        float acc = 0.0f;
        #pragma unroll
        for (int j = 0; j < C / 4; ++j) {
            float4 f = frow[j];
            acc = fmaf(f.x, w[4 * j + 0], acc);
            acc = fmaf(f.y, w[4 * j + 1], acc);
            acc = fmaf(f.z, w[4 * j + 2], acc);
            acc = fmaf(f.w, w[4 * j + 3], acc);
        }
        atomicAdd(out + (size_t)oi * C + lane, acc);
    }
}

__global__ __launch_bounds__(256)
void bn_relu_kernel(float* __restrict__ out,
                    const float* __restrict__ gamma,
                    const float* __restrict__ beta,
                    const float* __restrict__ mean,
                    const float* __restrict__ var)
{
    const int total4 = NOUT * C / 4;
    int idx = blockIdx.x * blockDim.x + threadIdx.x;
    if (idx >= total4) return;
    const int c0 = (idx * 4) & (C - 1);
    float sc[4], sh[4];
    #pragma unroll
    for (int j = 0; j < 4; ++j) {
        const int c  = c0 + j;
        const float s = gamma[c] * rsqrtf(var[c] + EPS);
        sc[j] = s;
        sh[j] = beta[c] - mean[c] * s;
    }
    float4* p = reinterpret_cast<float4*>(out) + idx;
    float4 v = *p;
    v.x = fmaf(v.x, sc[0], sh[0]); v.x = v.x > 0.f ? v.x : 0.f;
    v.y = fmaf(v.y, sc[1], sh[1]); v.y = v.y > 0.f ? v.y : 0.f;
    v.z = fmaf(v.z, sc[2], sh[2]); v.z = v.z > 0.f ? v.z : 0.f;
    v.w = fmaf(v.w, sc[3], sh[3]); v.w = v.w > 0.f ? v.w : 0.f;
    *p = v;
}

// ---------------------------------------------------------------------------
extern "C" void kernel_launch(void* const* d_in, const int* in_sizes, int n_in,
                              void* d_out, int out_size, void* d_ws, size_t ws_size,
                              hipStream_t stream) {
    const float* feats   = (const float*)d_in[0];
    const float* weight  = (const float*)d_in[1];
    const int*   in_idx  = (const int*)  d_in[2];
    const int*   out_idx = (const int*)  d_in[3];
    const float* gamma   = (const float*)d_in[4];
    const float* beta    = (const float*)d_in[5];
    const float* rmean   = (const float*)d_in[6];
    const float* rvar    = (const float*)d_in[7];
    float* out = (float*)d_out;

    auto align = [](size_t x) { return (x + 255) & ~(size_t)255; };

    // kpg=9 (G=3): P chunk 115 MB (L3-friendly); CAPC=5760 sized for kpg<=9.
    int kpg = 0, G = 0;
    size_t oBin = 0, oGc = 0, oFo = 0, oFb = 0, oWb = 0, oP = 0;
    for (int t = 9; t >= 1; --t) {
        int g = (KOFF + t - 1) / t;
        size_t a = 0;
        size_t bi = a; a += align((size_t)g * NCRS * CAPC * 4);   // binned segments
        size_t gc = a; a += align((size_t)g * NCRS * 4);          // gcur
        size_t fo = a; a += align((size_t)g * NCRS * 9 * 4);      // fine offsets
        size_t fb = a; a += align((size_t)NIN * C * 2);           // feats bf16
        size_t wb = a; a += align((size_t)KOFF * C * C * 2);      // weight bf16
        size_t q_ = a; a += align((size_t)t * NIN * C * 2);       // P_chunk bf16
        if (a <= ws_size) {
            kpg = t; G = g;
            oBin = bi; oGc = gc; oFo = fo; oFb = fb; oWb = wb; oP = q_;
            break;
        }
    }

    if (kpg == 0) {
        hipMemsetAsync(out, 0, (size_t)out_size * sizeof(float), stream);
        dim3 grid(512, KOFF);
        conv_scatter_kernel<<<grid, 256, 0, stream>>>(feats, weight, in_idx, out_idx, out);
        const int total4 = NOUT * C / 4;
        bn_relu_kernel<<<(total4 + 255) / 256, 256, 0, stream>>>(out, gamma, beta, rmean, rvar);
        return;
    }

    char* ws = (char*)d_ws;
    uint32_t* binned = (uint32_t*)(ws + oBin);
    int* gcur        = (int*)(ws + oGc);
    int* foff        = (int*)(ws + oFo);
    ushort* featsb   = (ushort*)(ws + oFb);
    ushort* weightb  = (ushort*)(ws + oWb);
    ushort* P        = (ushort*)(ws + oP);

    // --- bf16 conversions ---
    {
        int n8f = NIN * C / 8;
        cvt_bf16_kernel<<<(n8f + 255) / 256, 256, 0, stream>>>(feats, featsb, n8f);
        int n8w = KOFF * C * C / 8;
        cvt_bf16_kernel<<<(n8w + 255) / 256, 256, 0, stream>>>(weight, weightb, n8w);
    }

    // --- Two-level binning ---
    hipMemsetAsync(gcur, 0, (size_t)G * NCRS * sizeof(int), stream);
    {
        int itemsPerGroup = kpg * NIN;
        int nbC = (itemsPerGroup + IPB_F - 1) / IPB_F;
        dim3 gC(nbC, G);
        bin_coarse_kernel<<<gC, 256, 0, stream>>>(in_idx, out_idx, gcur, binned, kpg);
        dim3 gFi(NCRS, G);
        bin_fine_kernel<<<gFi, 256, 0, stream>>>(gcur, binned, foff);
    }

    // --- Per-group: MFMA GEMM chunk, then fine-bucket gather into out ---
    for (int g = 0; g < G; ++g) {
        const int k0   = g * kpg;
        const int kcnt = (k0 + kpg <= KOFF) ? kpg : (KOFF - k0);

        dim3 grid(128, kcnt);
        gemm_mfma_kernel<<<grid, 256, 0, stream>>>(featsb, weightb, P, k0);

        dim3 ggrid(NCRS, 8);
        gather_bucket_kernel<<<ggrid, 256, 0, stream>>>(
            (const uint2*)P, binned, foff, g * NCRS,
            gamma, beta, rmean, rvar, out,
            /*accumulate=*/(g > 0), /*finalize=*/(g == G - 1));
    }
}

// Round 13
// 282.199 us; speedup vs baseline: 1.1158x; 1.0033x over previous
//
#include <hip/hip_runtime.h>
#include <hip/hip_bf16.h>
#include <stdint.h>

#define NIN    100000
#define NOUT   200000
#define KOFF   27
#define C      64
#define NPAIR  (KOFF * NIN)            // 2,700,000
#define EPS    1e-5f
#define NCRS   196                     // coarse buckets of 1024 output rows
#define CAPC   5760                    // per-(group,coarse) capacity (mean 4592 @kpg=9, +17 sigma)
#define IPB_F  2048                    // items per bin_coarse block (sorted writes)
#define RPF    128                     // rows per fine bucket
#define SIT    1024                    // sorted-item capacity per fine bucket (mean 574)

typedef __attribute__((ext_vector_type(8))) short bf16x8;
typedef __attribute__((ext_vector_type(4))) float f32x4;

// ---------------- fp32 -> bf16 conversion (8 elems / thread) ---------------
__global__ __launch_bounds__(256)
void cvt_bf16_kernel(const float* __restrict__ src, ushort* __restrict__ dst, int n8)
{
    int t = blockIdx.x * 256 + threadIdx.x;
    if (t >= n8) return;
    const float4* s4 = reinterpret_cast<const float4*>(src) + (size_t)t * 2;
    float4 a = s4[0], b = s4[1];
    float v[8] = {a.x, a.y, a.z, a.w, b.x, b.y, b.z, b.w};
    union { ushort u[8]; uint4 q; } pk;
    #pragma unroll
    for (int j = 0; j < 8; ++j) {
        __hip_bfloat16 h = __float2bfloat16(v[j]);
        pk.u[j] = *reinterpret_cast<ushort*>(&h);
    }
    reinterpret_cast<uint4*>(dst)[t] = pk.q;
}

// ---------------- Phase A: MFMA GEMM  P_chunk[lk] = feats @ W[k0+lk] -------
__global__ __launch_bounds__(256)
void gemm_mfma_kernel(const ushort* __restrict__ featsb,   // [NIN][C] bf16
                      const ushort* __restrict__ weightb,  // [KOFF][C][C] bf16
                      ushort* __restrict__ P,              // [kcnt][NIN][C] bf16
                      int k0)
{
    const int lk   = blockIdx.y;
    const int k    = k0 + lk;
    const int lane = threadIdx.x & 63;
    const int wave = threadIdx.x >> 6;
    const int m16  = lane & 15;
    const int q    = lane >> 4;        // 0..3

    const ushort* wb = weightb + (size_t)k * C * C;
    bf16x8 xf[4][2];
    #pragma unroll
    for (int nt = 0; nt < 4; ++nt)
        #pragma unroll
        for (int kc = 0; kc < 2; ++kc)
            #pragma unroll
            for (int j = 0; j < 8; ++j)
                xf[nt][kc][j] = (short)wb[(size_t)(kc * 32 + 8 * q + j) * C + nt * 16 + m16];

    ushort* Pk = P + (size_t)lk * NIN * C;
    const int tiles = NIN / 16;        // 6250 exactly

    for (int tile = blockIdx.x * 4 + wave; tile < tiles; tile += gridDim.x * 4) {
        const int mbase = tile * 16;
        const ushort* fr = featsb + (size_t)(mbase + m16) * C;
        bf16x8 y0 = *reinterpret_cast<const bf16x8*>(fr + 8 * q);
        bf16x8 y1 = *reinterpret_cast<const bf16x8*>(fr + 32 + 8 * q);

        f32x4 acc0 = {0,0,0,0}, acc1 = {0,0,0,0}, acc2 = {0,0,0,0}, acc3 = {0,0,0,0};
        acc0 = __builtin_amdgcn_mfma_f32_16x16x32_bf16(xf[0][0], y0, acc0, 0, 0, 0);
        acc1 = __builtin_amdgcn_mfma_f32_16x16x32_bf16(xf[1][0], y0, acc1, 0, 0, 0);
        acc2 = __builtin_amdgcn_mfma_f32_16x16x32_bf16(xf[2][0], y0, acc2, 0, 0, 0);
        acc3 = __builtin_amdgcn_mfma_f32_16x16x32_bf16(xf[3][0], y0, acc3, 0, 0, 0);
        acc0 = __builtin_amdgcn_mfma_f32_16x16x32_bf16(xf[0][1], y1, acc0, 0, 0, 0);
        acc1 = __builtin_amdgcn_mfma_f32_16x16x32_bf16(xf[1][1], y1, acc1, 0, 0, 0);
        acc2 = __builtin_amdgcn_mfma_f32_16x16x32_bf16(xf[2][1], y1, acc2, 0, 0, 0);
        acc3 = __builtin_amdgcn_mfma_f32_16x16x32_bf16(xf[3][1], y1, acc3, 0, 0, 0);

        ushort* prow = Pk + (size_t)(mbase + m16) * C;
        f32x4 accs[4] = {acc0, acc1, acc2, acc3};
        #pragma unroll
        for (int nt = 0; nt < 4; ++nt) {
            union { ushort u[4]; uint2 v; } pk;
            #pragma unroll
            for (int r = 0; r < 4; ++r) {
                __hip_bfloat16 h = __float2bfloat16(accs[nt][r]);
                pk.u[r] = *reinterpret_cast<ushort*>(&h);
            }
            *reinterpret_cast<uint2*>(prow + nt * 16 + q * 4) = pk.v;
        }
    }
}

// ---------------- Phase B1: coarse binning with SORTED writes --------------
// Each block counting-sorts its IPB_F items by coarse bucket in LDS, then
// streams them out in sorted order: consecutive threads write consecutive
// addresses within each bucket run (~10x fewer store transactions than
// scattered placement). gcur is reservation cursor AND final count.
// Payload: bits[0,17)=ii  bits[17,21)=lk  bits[21,31)=oi&1023 (row in coarse).
__global__ __launch_bounds__(256)
void bin_coarse_kernel(const int* __restrict__ in_idx, const int* __restrict__ out_idx,
                       int* __restrict__ gcur, uint32_t* __restrict__ binned,
                       int kpg)
{
    __shared__ uint32_t staged[IPB_F];     // 8 KB: payloads in sorted order
    __shared__ ushort   sbkt[IPB_F];       // 4 KB: bucket of each sorted slot
    __shared__ int hist[NCRS];
    __shared__ int lbase[NCRS + 1];
    __shared__ int gd[NCRS];               // global_base - local_base
    __shared__ int cur[NCRS];
    __shared__ int s[256];

    const int g    = blockIdx.y;
    const int kbeg = g * kpg;
    const int tbeg = kbeg * NIN;
    const int t    = threadIdx.x;
    int tend = (g + 1) * kpg * NIN;
    if (tend > NPAIR) tend = NPAIR;
    const int t0 = tbeg + blockIdx.x * IPB_F;
    int n = tend - t0;
    if (n < 0) n = 0;
    if (n > IPB_F) n = IPB_F;

    for (int i = t; i < NCRS; i += 256) hist[i] = 0;
    __syncthreads();

    // pass 1: histogram by coarse bucket
    #pragma unroll 4
    for (int j = 0; j < IPB_F / 256; ++j) {
        int i = j * 256 + t;
        if (i < n) atomicAdd(&hist[out_idx[t0 + i] >> 10], 1);
    }
    __syncthreads();

    // in-block exclusive scan (NCRS <= 256, one bucket per thread)
    {
        int v = (t < NCRS) ? hist[t] : 0;
        s[t] = v;
        __syncthreads();
        for (int off = 1; off < 256; off <<= 1) {
            int x = (t >= off) ? s[t - off] : 0;
            __syncthreads();
            s[t] += x;
            __syncthreads();
        }
        if (t < NCRS) lbase[t] = s[t] - v;
        if (t == 255) lbase[NCRS] = s[255];
    }
    __syncthreads();

    // reserve global ranges; precompute write delta
    {
        int* gc = gcur + (size_t)g * NCRS;
        if (t < NCRS) {
            int cnt = hist[t];
            int gb  = cnt ? atomicAdd(&gc[t], cnt) : 0;
            gd[t]   = gb - lbase[t];
            cur[t]  = lbase[t];
        }
    }
    __syncthreads();

    // pass 2: place payloads into staged[] in bucket-sorted order
    #pragma unroll 4
    for (int j = 0; j < IPB_F / 256; ++j) {
        int i = j * 256 + t;
        if (i < n) {
            int tt  = t0 + i;
            int oi  = out_idx[tt];
            int k   = tt / NIN;
            int bkt = oi >> 10;
            int pos = atomicAdd(&cur[bkt], 1);
            staged[pos] = ((uint32_t)(oi & 1023) << 21)
                        | ((uint32_t)(k - kbeg) << 17)
                        | (uint32_t)in_idx[tt];
            sbkt[pos] = (ushort)bkt;
        }
    }
    __syncthreads();

    // pass 3: stream out in sorted order (coalesced within runs)
    for (int i = t; i < n; i += 256) {
        int b  = sbkt[i];
        int gp = gd[b] + i;                       // position within segment
        if ((unsigned)gp < (unsigned)CAPC)
            binned[((size_t)g * NCRS + b) * CAPC + gp] = staged[i];
    }
}

// ---------------- Phase B2: fine sort within coarse segment (in place) -----
// One block per (g, cb): counting-sort ~4.6K items by fine bucket
// ((row10>>7)&7, 128 rows each) in LDS, stream back to the SAME segment
// (reads complete before writes within the block), emit 9-entry offset table.
__global__ __launch_bounds__(256)
void bin_fine_kernel(const int* __restrict__ gcur, uint32_t* __restrict__ binned,
                     int* __restrict__ foff)
{
    __shared__ uint32_t staged[CAPC];
    __shared__ int hist8[8], base8[9], cur8[8];

    const int g  = blockIdx.y;
    const int cb = blockIdx.x;
    const int t  = threadIdx.x;
    const size_t segoff = ((size_t)g * NCRS + cb) * CAPC;
    uint32_t* seg = binned + segoff;
    int n = gcur[g * NCRS + cb];
    if (n > CAPC) n = CAPC;

    if (t < 8) hist8[t] = 0;
    __syncthreads();
    for (int i = t; i < n; i += 256)
        atomicAdd(&hist8[(seg[i] >> 28) & 7], 1);
    __syncthreads();
    if (t == 0) {
        int s = 0;
        #pragma unroll
        for (int b = 0; b < 8; ++b) { base8[b] = s; s += hist8[b]; }
        base8[8] = s;
    }
    __syncthreads();
    if (t < 8) cur8[t] = base8[t];
    __syncthreads();
    for (int i = t; i < n; i += 256) {
        uint32_t pl = seg[i];
        int pos = atomicAdd(&cur8[(pl >> 28) & 7], 1);
        staged[pos] = pl;
    }
    __syncthreads();
    for (int i = t; i < n; i += 256) seg[i] = staged[i];
    if (t <= 8) foff[((size_t)g * NCRS + cb) * 9 + t] = base8[t];
}

// ---------------- Phase C: per-fine-bucket gather + BN/ReLU ----------------
// Block = (cb, fb): 128 output rows, reads ONLY its contiguous fine run.
// Counting-sort by row, then 16 threads/row reduce P rows with 4-deep ILP.
__global__ __launch_bounds__(256)
void gather_bucket_kernel(const uint2* __restrict__ P2,
                          const uint32_t* __restrict__ binned,
                          const int* __restrict__ foff, int gbase,
                          const float* __restrict__ gamma,
                          const float* __restrict__ beta,
                          const float* __restrict__ mean,
                          const float* __restrict__ var,
                          float* __restrict__ out,
                          int accumulate, int finalize)
{
    __shared__ uint32_t sIt[SIT];
    __shared__ int sCnt[RPF];
    __shared__ int sOff[RPF + 1];
    __shared__ int sCur[RPF];

    const int cb = blockIdx.x;
    const int fb = blockIdx.y;                   // 0..7
    const int t  = threadIdx.x;
    const int* fo = foff + ((size_t)(gbase + cb)) * 9;
    const int js = fo[fb], je = fo[fb + 1];
    const uint32_t* seg = binned + ((size_t)(gbase + cb)) * CAPC;

    if (t < RPF) sCnt[t] = 0;
    __syncthreads();
    for (int i = js + t; i < je; i += 256)
        atomicAdd(&sCnt[(seg[i] >> 21) & 127], 1);
    __syncthreads();
    if (t < RPF) sOff[t + 1] = sCnt[t];
    __syncthreads();
    for (int off = 1; off < RPF; off <<= 1) {
        int x = 0;
        if (t < RPF && t >= off) x = sOff[t + 1 - off];
        __syncthreads();
        if (t < RPF) sOff[t + 1] += x;
        __syncthreads();
    }
    if (t == 0) sOff[0] = 0;
    __syncthreads();
    if (t < RPF) sCur[t] = sOff[t + 1] - sCnt[t];
    __syncthreads();
    for (int i = js + t; i < je; i += 256) {
        uint32_t pl = seg[i];
        int slot = atomicAdd(&sCur[(pl >> 21) & 127], 1);
        if (slot < SIT) sIt[slot] = pl;
    }
    __syncthreads();

    const int cp = t & 15;
    const int c0 = cp * 4;
    float sc[4], sh[4];
    if (finalize) {
        #pragma unroll
        for (int r = 0; r < 4; ++r) {
            const int c = c0 + r;
            float s = gamma[c] * rsqrtf(var[c] + EPS);
            sc[r] = s;
            sh[r] = beta[c] - mean[c] * s;
        }
    }

    float4* out4 = reinterpret_cast<float4*>(out);
    #pragma unroll 1
    for (int it = 0; it < RPF / 16; ++it) {
        const int rl  = (t >> 4) + it * 16;
        const int row = cb * 1024 + fb * 128 + rl;
        if (row >= NOUT) continue;
        int j  = sOff[rl];
        const int jend = sOff[rl + 1];

        float a0 = 0.f, a1 = 0.f, a2 = 0.f, a3 = 0.f;
        for (; j + 3 < jend; j += 4) {            // 4 loads in flight
            uint32_t p0 = sIt[j],     p1 = sIt[j + 1];
            uint32_t p2 = sIt[j + 2], p3 = sIt[j + 3];
            uint2 u0 = P2[((size_t)((p0 >> 17) & 15) * NIN + (p0 & 0x1FFFF)) * 16 + cp];
            uint2 u1 = P2[((size_t)((p1 >> 17) & 15) * NIN + (p1 & 0x1FFFF)) * 16 + cp];
            uint2 u2 = P2[((size_t)((p2 >> 17) & 15) * NIN + (p2 & 0x1FFFF)) * 16 + cp];
            uint2 u3 = P2[((size_t)((p3 >> 17) & 15) * NIN + (p3 & 0x1FFFF)) * 16 + cp];
            a0 += __uint_as_float(u0.x << 16);
            a1 += __uint_as_float(u0.x & 0xffff0000u);
            a2 += __uint_as_float(u0.y << 16);
            a3 += __uint_as_float(u0.y & 0xffff0000u);
            a0 += __uint_as_float(u1.x << 16);
            a1 += __uint_as_float(u1.x & 0xffff0000u);
            a2 += __uint_as_float(u1.y << 16);
            a3 += __uint_as_float(u1.y & 0xffff0000u);
            a0 += __uint_as_float(u2.x << 16);
            a1 += __uint_as_float(u2.x & 0xffff0000u);
            a2 += __uint_as_float(u2.y << 16);
            a3 += __uint_as_float(u2.y & 0xffff0000u);
            a0 += __uint_as_float(u3.x << 16);
            a1 += __uint_as_float(u3.x & 0xffff0000u);
            a2 += __uint_as_float(u3.y << 16);
            a3 += __uint_as_float(u3.y & 0xffff0000u);
        }
        for (; j < jend; ++j) {
            uint32_t p0 = sIt[j];
            uint2 u0 = P2[((size_t)((p0 >> 17) & 15) * NIN + (p0 & 0x1FFFF)) * 16 + cp];
            a0 += __uint_as_float(u0.x << 16);
            a1 += __uint_as_float(u0.x & 0xffff0000u);
            a2 += __uint_as_float(u0.y << 16);
            a3 += __uint_as_float(u0.y & 0xffff0000u);
        }

        const size_t oidx = (size_t)row * 16 + cp;
        if (accumulate) {
            float4 pv = out4[oidx];
            a0 += pv.x; a1 += pv.y; a2 += pv.z; a3 += pv.w;
        }
        if (finalize) {
            a0 = fmaf(a0, sc[0], sh[0]); a0 = a0 > 0.f ? a0 : 0.f;
            a1 = fmaf(a1, sc[1], sh[1]); a1 = a1 > 0.f ? a1 : 0.f;
            a2 = fmaf(a2, sc[2], sh[2]); a2 = a2 > 0.f ? a2 : 0.f;
            a3 = fmaf(a3, sc[3], sh[3]); a3 = a3 > 0.f ? a3 : 0.f;
        }
        out4[oidx] = make_float4(a0, a1, a2, a3);
    }
}

// ---------------- Fallback (atomic path, tiny ws) --------------------------
__global__ __launch_bounds__(256)
void conv_scatter_kernel(const float* __restrict__ feats,
                         const float* __restrict__ weight,
                         const int*   __restrict__ in_idx,
                         const int*   __restrict__ out_idx,
                         float*       __restrict__ out)
{
    const int k    = blockIdx.y;
    const int lane = threadIdx.x & 63;
    const int wave = threadIdx.x >> 6;
    const int wavesInGrid = gridDim.x * 4;
    const int waveId      = blockIdx.x * 4 + wave;

    const float* wk = weight + (size_t)k * C * C + lane;
    float w[C];
    #pragma unroll
    for (int ci = 0; ci < C; ++ci) w[ci] = wk[(size_t)ci * C];

    const int* ii_k = in_idx  + (size_t)k * NIN;
    const int* oi_k = out_idx + (size_t)k * NIN;

    for (int r = waveId; r < NIN; r += wavesInGrid) {
        const int ii = ii_k[r];
        const int oi = oi_k[r];
        const float4* frow = reinterpret_cast<const float4*>(feats + (size_t)ii * C);
        float acc = 0.0f;
        #pragma unroll
        for (int j = 0; j < C / 4; ++j) {
            float4 f = frow[j];
            acc = fmaf(f.x, w[4 * j + 0], acc);
            acc = fmaf(f.y, w[4 * j + 1], acc);
            acc = fmaf(f.z, w[4 * j + 2], acc);
            acc = fmaf(f.w, w[4 * j + 3], acc);
        }
        atomicAdd(out + (size_t)oi * C + lane, acc);
    }
}

__global__ __launch_bounds__(256)
void bn_relu_kernel(float* __restrict__ out,
                    const float* __restrict__ gamma,
                    const float* __restrict__ beta,
                    const float* __restrict__ mean,
                    const float* __restrict__ var)
{
    const int total4 = NOUT * C / 4;
    int idx = blockIdx.x * blockDim.x + threadIdx.x;
    if (idx >= total4) return;
    const int c0 = (idx * 4) & (C - 1);
    float sc[4], sh[4];
    #pragma unroll
    for (int j = 0; j < 4; ++j) {
        const int c  = c0 + j;
        const float s = gamma[c] * rsqrtf(var[c] + EPS);
        sc[j] = s;
        sh[j] = beta[c] - mean[c] * s;
    }
    float4* p = reinterpret_cast<float4*>(out) + idx;
    float4 v = *p;
    v.x = fmaf(v.x, sc[0], sh[0]); v.x = v.x > 0.f ? v.x : 0.f;
    v.y = fmaf(v.y, sc[1], sh[1]); v.y = v.y > 0.f ? v.y : 0.f;
    v.z = fmaf(v.z, sc[2], sh[2]); v.z = v.z > 0.f ? v.z : 0.f;
    v.w = fmaf(v.w, sc[3], sh[3]); v.w = v.w > 0.f ? v.w : 0.f;
    *p = v;
}

// ---------------------------------------------------------------------------
extern "C" void kernel_launch(void* const* d_in, const int* in_sizes, int n_in,
                              void* d_out, int out_size, void* d_ws, size_t ws_size,
                              hipStream_t stream) {
    const float* feats   = (const float*)d_in[0];
    const float* weight  = (const float*)d_in[1];
    const int*   in_idx  = (const int*)  d_in[2];
    const int*   out_idx = (const int*)  d_in[3];
    const float* gamma   = (const float*)d_in[4];
    const float* beta    = (const float*)d_in[5];
    const float* rmean   = (const float*)d_in[6];
    const float* rvar    = (const float*)d_in[7];
    float* out = (float*)d_out;

    auto align = [](size_t x) { return (x + 255) & ~(size_t)255; };

    // kpg=9 (G=3): P chunk 115 MB (L3-friendly); CAPC=5760 sized for kpg<=9.
    int kpg = 0, G = 0;
    size_t oBin = 0, oGc = 0, oFo = 0, oFb = 0, oWb = 0, oP = 0;
    for (int t = 9; t >= 1; --t) {
        int g = (KOFF + t - 1) / t;
        size_t a = 0;
        size_t bi = a; a += align((size_t)g * NCRS * CAPC * 4);   // binned segments
        size_t gc = a; a += align((size_t)g * NCRS * 4);          // gcur
        size_t fo = a; a += align((size_t)g * NCRS * 9 * 4);      // fine offsets
        size_t fb = a; a += align((size_t)NIN * C * 2);           // feats bf16
        size_t wb = a; a += align((size_t)KOFF * C * C * 2);      // weight bf16
        size_t q_ = a; a += align((size_t)t * NIN * C * 2);       // P_chunk bf16
        if (a <= ws_size) {
            kpg = t; G = g;
            oBin = bi; oGc = gc; oFo = fo; oFb = fb; oWb = wb; oP = q_;
            break;
        }
    }

    if (kpg == 0) {
        hipMemsetAsync(out, 0, (size_t)out_size * sizeof(float), stream);
        dim3 grid(512, KOFF);
        conv_scatter_kernel<<<grid, 256, 0, stream>>>(feats, weight, in_idx, out_idx, out);
        const int total4 = NOUT * C / 4;
        bn_relu_kernel<<<(total4 + 255) / 256, 256, 0, stream>>>(out, gamma, beta, rmean, rvar);
        return;
    }

    char* ws = (char*)d_ws;
    uint32_t* binned = (uint32_t*)(ws + oBin);
    int* gcur        = (int*)(ws + oGc);
    int* foff        = (int*)(ws + oFo);
    ushort* featsb   = (ushort*)(ws + oFb);
    ushort* weightb  = (ushort*)(ws + oWb);
    ushort* P        = (ushort*)(ws + oP);

    // --- bf16 conversions ---
    {
        int n8f = NIN * C / 8;
        cvt_bf16_kernel<<<(n8f + 255) / 256, 256, 0, stream>>>(feats, featsb, n8f);
        int n8w = KOFF * C * C / 8;
        cvt_bf16_kernel<<<(n8w + 255) / 256, 256, 0, stream>>>(weight, weightb, n8w);
    }

    // --- Two-level binning ---
    hipMemsetAsync(gcur, 0, (size_t)G * NCRS * sizeof(int), stream);
    {
        int itemsPerGroup = kpg * NIN;
        int nbC = (itemsPerGroup + IPB_F - 1) / IPB_F;
        dim3 gC(nbC, G);
        bin_coarse_kernel<<<gC, 256, 0, stream>>>(in_idx, out_idx, gcur, binned, kpg);
        dim3 gFi(NCRS, G);
        bin_fine_kernel<<<gFi, 256, 0, stream>>>(gcur, binned, foff);
    }

    // --- Per-group: MFMA GEMM chunk, then fine-bucket gather into out ---
    for (int g = 0; g < G; ++g) {
        const int k0   = g * kpg;
        const int kcnt = (k0 + kpg <= KOFF) ? kpg : (KOFF - k0);

        dim3 grid(128, kcnt);
        gemm_mfma_kernel<<<grid, 256, 0, stream>>>(featsb, weightb, P, k0);

        dim3 ggrid(NCRS, 8);
        gather_bucket_kernel<<<ggrid, 256, 0, stream>>>(
            (const uint2*)P, binned, foff, g * NCRS,
            gamma, beta, rmean, rvar, out,
            /*accumulate=*/(g > 0), /*finalize=*/(g == G - 1));
    }
}